// Round 11
// baseline (725.710 us; speedup 1.0000x reference)
//
#include <hip/hip_runtime.h>
#include <hip/hip_bf16.h>

#define N_NODES 50000
#define N_PAD 50048           // padded rows for MFMA tiles (multiple of 64)
#define N_EDGES 1600000
#define ET (N_EDGES + N_NODES)
#define G_GRAPHS 128
#define NB 3125               // 16-node buckets: 3125*16 == 50000 exactly
#define LOG2E 1.4426950408889634f

typedef unsigned short ushort8v __attribute__((ext_vector_type(8)));
typedef unsigned short ushort4v __attribute__((ext_vector_type(4)));
typedef short bf16x8 __attribute__((ext_vector_type(8)));
typedef float f32x4 __attribute__((ext_vector_type(4)));

__device__ __forceinline__ float bf2f(unsigned short u)
{
    return __uint_as_float(((unsigned int)u) << 16);
}
__device__ __forceinline__ unsigned short f2bf(float f)
{
    unsigned int u = __float_as_uint(f);
    u = (u + 0x7FFFu + ((u >> 16) & 1u)) >> 16;
    return (unsigned short)u;
}
__device__ __forceinline__ float exp2fast(float x) { return __builtin_amdgcn_exp2f(x); }
__device__ __forceinline__ float lrelu(float x) { return fmaxf(x, 0.2f * x); }

// ---------------- small utility kernels ----------------

__global__ void ea_sum_kernel(const float* __restrict__ ea, float* __restrict__ out, int n)
{
    float s = 0.f;
    for (int i = blockIdx.x * blockDim.x + threadIdx.x; i < n; i += gridDim.x * blockDim.x)
        s += ea[i];
    #pragma unroll
    for (int off = 32; off; off >>= 1) s += __shfl_xor(s, off);
    if ((threadIdx.x & 63) == 0) atomicAdd(out, s);
}

// ws scalars layout: [0]=ea_sum [1]=ea_mean [2..5]=c1[4]*log2e [6]=c2*log2e
__global__ void scalars_kernel(float* __restrict__ ws,
                               const float* __restrict__ We1, const float* __restrict__ ae1,
                               const float* __restrict__ We2, const float* __restrict__ ae2)
{
    if (threadIdx.x == 0 && blockIdx.x == 0) {
        ws[1] = ws[0] / (float)N_EDGES;
        for (int h = 0; h < 4; ++h) {
            float c = 0.f;
            for (int o = 0; o < 64; ++o) c += We1[h * 64 + o] * ae1[h * 64 + o];
            ws[2 + h] = c * LOG2E;
        }
        float c2 = 0.f;
        for (int o = 0; o < 64; ++o) c2 += We2[o] * ae2[o];
        ws[6] = c2 * LOG2E;
    }
}

// count edges per 16-node bucket
__global__ void bcount_kernel(const int* __restrict__ ei, int* __restrict__ bcount)
{
    int e = blockIdx.x * blockDim.x + threadIdx.x;
    if (e >= ET) return;
    int dst = (e < N_EDGES) ? ei[N_EDGES + e] : (e - N_EDGES);
    atomicAdd(&bcount[dst >> 4], 1);
}

// prefix over NB bucket counts -> bstart[NB+1], bcur[NB]
__global__ __launch_bounds__(1024) void bscan_kernel(const int* __restrict__ bcount,
                                                     int* __restrict__ bstart,
                                                     int* __restrict__ bcur)
{
    __shared__ int ssum[1024];
    const int C = (NB + 1023) / 1024;   // 4
    int tid = threadIdx.x;
    int c0 = tid * C, c1 = min(c0 + C, NB);
    int s = 0;
    for (int i = c0; i < c1; ++i) s += bcount[i];
    ssum[tid] = s;
    __syncthreads();
    for (int off = 1; off < 1024; off <<= 1) {
        int v = (tid >= off) ? ssum[tid - off] : 0;
        __syncthreads();
        ssum[tid] += v;
        __syncthreads();
    }
    int run = ssum[tid] - s;  // exclusive prefix
    for (int i = c0; i < c1; ++i) { bstart[i] = run; bcur[i] = run; run += bcount[i]; }
    if (tid == 1023) bstart[NB] = ET;
}

// scatter packed record {ea:32 | src:17 | dstlo:4} to bucket region (line-local fronts)
__global__ void binscatter_kernel(const int* __restrict__ ei, const float* __restrict__ ea,
                                  const float* __restrict__ ws, int* __restrict__ bcur,
                                  unsigned long long* __restrict__ bstage)
{
    int e = blockIdx.x * blockDim.x + threadIdx.x;
    if (e >= ET) return;
    int src, dst; float v;
    if (e < N_EDGES) { src = ei[e]; dst = ei[N_EDGES + e]; v = ea[e]; }
    else             { src = dst = e - N_EDGES; v = ws[1]; }
    int pos = atomicAdd(&bcur[dst >> 4], 1);
    unsigned long long rec = ((unsigned long long)__float_as_uint(v) << 32)
                           | ((unsigned)src << 4) | (unsigned)(dst & 15);
    bstage[pos] = rec;
}

// per-bucket: LDS degree count -> rowstart for 16 nodes -> LDS-cursor scatter to CSR
__global__ __launch_bounds__(256) void bucketfill_kernel(const int* __restrict__ bstart,
                                                         const unsigned long long* __restrict__ bstage,
                                                         int* __restrict__ rowstart,
                                                         uint2* __restrict__ csr)
{
    __shared__ int lcnt[16];
    __shared__ int lcur[16];
    int b = blockIdx.x;
    int s = bstart[b], e = bstart[b + 1];
    int tid = threadIdx.x;
    if (tid < 16) lcnt[tid] = 0;
    __syncthreads();
    for (int p = s + tid; p < e; p += 256)
        atomicAdd(&lcnt[(int)(bstage[p] & 15)], 1);
    __syncthreads();
    if (tid == 0) {
        int run = s;
        #pragma unroll
        for (int i = 0; i < 16; ++i) { lcur[i] = run; rowstart[b * 16 + i] = run; run += lcnt[i]; }
        if (b == NB - 1) rowstart[N_NODES] = ET;
    }
    __syncthreads();
    for (int p = s + tid; p < e; p += 256) {
        unsigned long long rec = bstage[p];
        int pos = atomicAdd(&lcur[(int)(rec & 15)], 1);
        csr[pos] = make_uint2((unsigned)((rec >> 4) & 0x1FFFFu), (unsigned)(rec >> 32));
    }
}

// graph start offsets in the sorted batch_idx (129 entries)
__global__ void gstart_kernel(const int* __restrict__ bidx, int* __restrict__ gstart)
{
    int g = blockIdx.x * blockDim.x + threadIdx.x;
    if (g > G_GRAPHS) return;
    int lo = 0, hi = N_NODES;
    while (lo < hi) { int mid = (lo + hi) >> 1; if (bidx[mid] < g) lo = mid + 1; else hi = mid; }
    gstart[g] = lo;
}

// transpose+cast weights: W1[128][256]->W1t[256][128] bf16; W2[256][64]->W2t[64][256] bf16
__global__ void wcast_kernel(const float* __restrict__ W1, const float* __restrict__ W2,
                             unsigned short* __restrict__ W1t, unsigned short* __restrict__ W2t)
{
    int i = blockIdx.x * blockDim.x + threadIdx.x;
    if (i < 128 * 256) { int k = i >> 8, c = i & 255; W1t[c * 128 + k] = f2bf(W1[i]); }
    if (i < 256 * 64)  { int k = i >> 6, c = i & 63;  W2t[c * 256 + k] = f2bf(W2[i]); }
}

// ---------------- MFMA bf16 GEMM + fused alpha projections ----------------
template <int K, int NCB, bool A_F32, int NHEADS>
__global__ __launch_bounds__(256) void gemm_mfma(const void* __restrict__ Av,
                                                 const unsigned short* __restrict__ Wt,
                                                 unsigned short* __restrict__ C,
                                                 const float* __restrict__ a_s,
                                                 const float* __restrict__ a_d,
                                                 float* __restrict__ asrc,
                                                 float* __restrict__ adst,
                                                 int M)
{
    const int NC = NCB * 16;
    int wave = threadIdx.x >> 6, lane = threadIdx.x & 63;
    int l16 = lane & 15, lk = lane >> 4;
    int m = blockIdx.x * 64 + wave * 16 + l16;
    if (m >= M) m = M - 1;                 // clamp: tail lanes duplicate row M-1 (benign)
    f32x4 acc[NCB] = {};
    #pragma unroll
    for (int k0 = 0; k0 < K; k0 += 32) {
        int kk = k0 + lk * 8;
        bf16x8 af;
        if constexpr (A_F32) {
            const float* A = (const float*)Av;
            float4 u0 = *(const float4*)&A[(size_t)m * K + kk];
            float4 u1 = *(const float4*)&A[(size_t)m * K + kk + 4];
            af[0] = (short)f2bf(u0.x); af[1] = (short)f2bf(u0.y);
            af[2] = (short)f2bf(u0.z); af[3] = (short)f2bf(u0.w);
            af[4] = (short)f2bf(u1.x); af[5] = (short)f2bf(u1.y);
            af[6] = (short)f2bf(u1.z); af[7] = (short)f2bf(u1.w);
        } else {
            af = *(const bf16x8*)&((const unsigned short*)Av)[(size_t)m * K + kk];
        }
        #pragma unroll
        for (int cb = 0; cb < NCB; ++cb) {
            bf16x8 wf = *(const bf16x8*)&Wt[(size_t)(cb * 16 + l16) * K + kk];
            acc[cb] = __builtin_amdgcn_mfma_f32_16x16x32_bf16(wf, af, acc[cb], 0, 0, 0);
        }
    }
    float sa[NHEADS], da[NHEADS];
    #pragma unroll
    for (int h = 0; h < NHEADS; ++h) { sa[h] = 0.f; da[h] = 0.f; }
    #pragma unroll
    for (int cb = 0; cb < NCB; ++cb) {
        const int hh = (NHEADS == 4) ? (cb >> 2) : 0;
        ushort4v o;
        #pragma unroll
        for (int j = 0; j < 4; ++j) {
            o[j] = f2bf(acc[cb][j]);
            float v = bf2f(o[j]);           // use rounded value (matches gather path)
            int c = cb * 16 + lk * 4 + j;
            sa[hh] = fmaf(v, a_s[c], sa[hh]);
            da[hh] = fmaf(v, a_d[c], da[hh]);
        }
        *(ushort4v*)&C[(size_t)m * NC + cb * 16 + lk * 4] = o;
    }
    #pragma unroll
    for (int h = 0; h < NHEADS; ++h) {
        sa[h] += __shfl_xor(sa[h], 16); sa[h] += __shfl_xor(sa[h], 32);
        da[h] += __shfl_xor(da[h], 16); da[h] += __shfl_xor(da[h], 32);
    }
    if (lk == 0) {
        if constexpr (NHEADS == 4) {
            float4 vs = make_float4(sa[0] * LOG2E, sa[1] * LOG2E, sa[2] * LOG2E, sa[3] * LOG2E);
            float4 vd = make_float4(da[0] * LOG2E, da[1] * LOG2E, da[2] * LOG2E, da[3] * LOG2E);
            *(float4*)&asrc[(size_t)m * 4] = vs;
            *(float4*)&adst[(size_t)m * 4] = vd;
        } else {
            asrc[m] = sa[0] * LOG2E;
            adst[m] = da[0] * LOG2E;
        }
    }
}

// ---------------- layer 1: single-pass softmax-aggregate (exp2 domain) ----------------
// 2 lane-groups x 32 lanes; lane covers 8 channels; 8 loads = 16 edges/iter.

__global__ __launch_bounds__(256) void agg1_kernel(const int* __restrict__ rowstart,
                                                   const uint2* __restrict__ csr,
                                                   const float* __restrict__ asrc,
                                                   const float* __restrict__ adst,
                                                   const float* __restrict__ ws,
                                                   const unsigned short* __restrict__ h1bf,
                                                   const float* __restrict__ b1,
                                                   unsigned short* __restrict__ h1rbf)
{
    int wid  = (blockIdx.x * blockDim.x + threadIdx.x) >> 6;
    int lane = threadIdx.x & 63;
    if (wid >= N_NODES) return;
    int rs = rowstart[wid], re = rowstart[wid + 1];
    int g   = lane >> 5;        // edge sub-slot (0..1)
    int sub = lane & 31;        // channel block: channels sub*8 .. sub*8+7
    int hh  = sub >> 3;         // head of this lane's channels
    float ad_s = adst[(size_t)wid * 4 + hh];
    float c_s  = ws[2 + hh];

    float acc[8] = {};
    float sden = 0.f;
    for (int p = rs; p < re; p += 16) {
        #pragma unroll
        for (int k = 0; k < 8; ++k) {
            int pe = p + 2 * k + g;
            bool act = pe < re;
            int idx = act ? pe : re - 1;
            uint2 q = csr[idx];
            int src  = (int)q.x;
            float ev = __uint_as_float(q.y);
            ushort8v r = *(const ushort8v*)&h1bf[(size_t)src * 256 + sub * 8];
            float al = lrelu(fmaf(ev, c_s, asrc[(size_t)src * 4 + hh] + ad_s));
            float wgt = act ? exp2fast(al) : 0.f;
            sden += wgt;
            #pragma unroll
            for (int j = 0; j < 8; ++j)
                acc[j] = fmaf(bf2f(r[j]), wgt, acc[j]);
        }
    }
    sden += __shfl_xor(sden, 32);
    #pragma unroll
    for (int j = 0; j < 8; ++j) acc[j] += __shfl_xor(acc[j], 32);
    float inv = 1.0f / (sden + 1e-16f);
    if (g == 0) {
        float4 ba = *(const float4*)&b1[sub * 8];
        float4 bb = *(const float4*)&b1[sub * 8 + 4];
        ushort8v ov;
        ov[0] = f2bf(fmaxf(fmaf(acc[0], inv, ba.x), 0.f));
        ov[1] = f2bf(fmaxf(fmaf(acc[1], inv, ba.y), 0.f));
        ov[2] = f2bf(fmaxf(fmaf(acc[2], inv, ba.z), 0.f));
        ov[3] = f2bf(fmaxf(fmaf(acc[3], inv, ba.w), 0.f));
        ov[4] = f2bf(fmaxf(fmaf(acc[4], inv, bb.x), 0.f));
        ov[5] = f2bf(fmaxf(fmaf(acc[5], inv, bb.y), 0.f));
        ov[6] = f2bf(fmaxf(fmaf(acc[6], inv, bb.z), 0.f));
        ov[7] = f2bf(fmaxf(fmaf(acc[7], inv, bb.w), 0.f));
        *(ushort8v*)&h1rbf[(size_t)wid * 256 + sub * 8] = ov;
    }
}

// ---------------- layer 2 (H=1): single-pass softmax-aggregate, direct store ----------------
// 8 lane-groups x 8 lanes; lane covers 8 channels; 4 loads = 32 edges/iter.

__global__ __launch_bounds__(256) void agg2_kernel(const int* __restrict__ rowstart,
                                                   const uint2* __restrict__ csr,
                                                   const float* __restrict__ asrc,
                                                   const float* __restrict__ adst,
                                                   const float* __restrict__ ws,
                                                   const unsigned short* __restrict__ h2bf,
                                                   const float* __restrict__ b2,
                                                   float* __restrict__ h2out)
{
    int wid  = (blockIdx.x * blockDim.x + threadIdx.x) >> 6;
    int lane = threadIdx.x & 63;
    if (wid >= N_NODES) return;
    int rs = rowstart[wid], re = rowstart[wid + 1];
    float c2 = ws[6];
    float ad = adst[wid];
    int g   = lane >> 3;   // edge sub-slot (0..7)
    int sub = lane & 7;    // channel block: channels sub*8 .. sub*8+7
    float acc[8] = {};
    float sden = 0.f;
    for (int p = rs; p < re; p += 32) {
        #pragma unroll
        for (int k = 0; k < 4; ++k) {
            int pe = p + 8 * k + g;
            bool act = pe < re;
            int idx = act ? pe : re - 1;
            uint2 q = csr[idx];
            int src  = (int)q.x;
            float ev = __uint_as_float(q.y);
            ushort8v r = *(const ushort8v*)&h2bf[(size_t)src * 64 + sub * 8];
            float al = lrelu(fmaf(ev, c2, asrc[src] + ad));
            float wgt = act ? exp2fast(al) : 0.f;
            sden += wgt;
            #pragma unroll
            for (int j = 0; j < 8; ++j)
                acc[j] = fmaf(bf2f(r[j]), wgt, acc[j]);
        }
    }
    sden += __shfl_xor(sden, 8);
    sden += __shfl_xor(sden, 16);
    sden += __shfl_xor(sden, 32);
    #pragma unroll
    for (int j = 0; j < 8; ++j) {
        acc[j] += __shfl_xor(acc[j], 8);
        acc[j] += __shfl_xor(acc[j], 16);
        acc[j] += __shfl_xor(acc[j], 32);
    }
    float inv = 1.0f / (sden + 1e-16f);
    if (g == 0) {
        float4 ba = *(const float4*)&b2[sub * 8];
        float4 bb = *(const float4*)&b2[sub * 8 + 4];
        float4 o0, o1;
        o0.x = fmaf(acc[0], inv, ba.x); o0.y = fmaf(acc[1], inv, ba.y);
        o0.z = fmaf(acc[2], inv, ba.z); o0.w = fmaf(acc[3], inv, ba.w);
        o1.x = fmaf(acc[4], inv, bb.x); o1.y = fmaf(acc[5], inv, bb.y);
        o1.z = fmaf(acc[6], inv, bb.z); o1.w = fmaf(acc[7], inv, bb.w);
        float* o = h2out + (size_t)wid * 64 + sub * 8;
        *(float4*)&o[0] = o0;
        *(float4*)&o[4] = o1;
    }
}

// ---------------- fused mean pool + MLP head: one block per graph ----------------

__global__ __launch_bounds__(256) void pool_mlp_kernel(const float* __restrict__ h2out,
                                                       const int* __restrict__ gstart,
                                                       const float* __restrict__ Wl1,
                                                       const float* __restrict__ bl1,
                                                       const float* __restrict__ lng,
                                                       const float* __restrict__ lnb,
                                                       const float* __restrict__ Wl2,
                                                       const float* __restrict__ bl2,
                                                       float* __restrict__ out)
{
    __shared__ float sh[4][64];
    __shared__ float gs[64], zs[64];
    int g = blockIdx.x;
    int wv = threadIdx.x >> 6, lane = threadIdx.x & 63;
    int s = gstart[g], e = gstart[g + 1];
    float acc = 0.f;
    for (int n = s + wv; n < e; n += 4)
        acc += h2out[(size_t)n * 64 + lane];
    sh[wv][lane] = acc;
    __syncthreads();
    int l = threadIdx.x;
    if (l < 64) {
        float cnt = fmaxf((float)(e - s), 1.f);
        gs[l] = (sh[0][l] + sh[1][l] + sh[2][l] + sh[3][l]) / cnt;
    }
    __syncthreads();
    if (l < 64) {
        float z = bl1[l];
        for (int k = 0; k < 64; ++k) z = fmaf(gs[k], Wl1[k * 64 + l], z);
        z = fmaxf(z, 0.f);
        float sum = z;
        #pragma unroll
        for (int off = 32; off; off >>= 1) sum += __shfl_xor(sum, off);
        float mu = sum * (1.f / 64.f);
        float d  = z - mu;
        float vs = d * d;
        #pragma unroll
        for (int off = 32; off; off >>= 1) vs += __shfl_xor(vs, off);
        float var = vs * (1.f / 64.f);
        zs[l] = d * rsqrtf(var + 1e-5f) * lng[l] + lnb[l];
    }
    __syncthreads();
    if (l < 16) {
        float o = bl2[l];
        for (int k = 0; k < 64; ++k) o = fmaf(zs[k], Wl2[k * 16 + l], o);
        out[g * 16 + l] = o;
    }
}

__global__ void copy_ea_kernel(const float* __restrict__ ea, float* __restrict__ out)
{
    for (int i = blockIdx.x * blockDim.x + threadIdx.x; i < N_EDGES; i += gridDim.x * blockDim.x)
        out[i] = ea[i];
}

// ---------------- launch ----------------

extern "C" void kernel_launch(void* const* d_in, const int* in_sizes, int n_in,
                              void* d_out, int out_size, void* d_ws, size_t ws_size,
                              hipStream_t stream)
{
    const float* x    = (const float*)d_in[0];
    const int*   ei   = (const int*)d_in[1];
    const float* ea   = (const float*)d_in[2];
    const int*   bidx = (const int*)d_in[3];
    const float* W1   = (const float*)d_in[4];
    const float* as1  = (const float*)d_in[5];
    const float* ad1  = (const float*)d_in[6];
    const float* We1  = (const float*)d_in[7];
    const float* ae1  = (const float*)d_in[8];
    const float* b1   = (const float*)d_in[9];
    const float* W2   = (const float*)d_in[10];
    const float* as2  = (const float*)d_in[11];
    const float* ad2  = (const float*)d_in[12];
    const float* We2  = (const float*)d_in[13];
    const float* ae2  = (const float*)d_in[14];
    const float* b2   = (const float*)d_in[15];
    const float* Wl1  = (const float*)d_in[16];
    const float* bl1  = (const float*)d_in[17];
    const float* lng  = (const float*)d_in[18];
    const float* lnb  = (const float*)d_in[19];
    const float* Wl2  = (const float*)d_in[20];
    const float* bl2  = (const float*)d_in[21];
    float* out = (float*)d_out;

    char* w = (char*)d_ws;
    float* scalars  = (float*)(w + 0);            // 64 B
    int*   bcount   = (int*)  (w + 64);           // 12500 B -> 12564
    const size_t zbytes = 12608;                  // zero scalars + bcount
    int*   bstart   = (int*)  (w + 12608);        // 12504 -> 25112
    int*   bcur     = (int*)  (w + 25152);        // 12500 -> 37652
    int*   rowstart = (int*)  (w + 37696);        // 200004 -> 237700
    int*   gstart   = (int*)  (w + 237760);       // 516 -> 238276
    unsigned long long* bstage = (unsigned long long*)(w + 238336);  // 13.2 MB -> 13438336
    uint2* csr      = (uint2*)(w + 13438336);     // 13.2 MB -> 26638336
    float* asrc1    = (float*)(w + 26638336);     // 800 KB
    float* adst1    = (float*)(w + 27438336);     // 800 KB
    float* asrc2    = (float*)(w + 28238336);     // 200 KB
    float* adst2    = (float*)(w + 28438336);     // 200 KB -> 28638336
    unsigned short* W1t  = (unsigned short*)(w + 28638336);   // 64 KB -> 28703872
    unsigned short* W2t  = (unsigned short*)(w + 28703872);   // 32 KB -> 28736640
    unsigned short* h1bf = (unsigned short*)(w + 28736640);   // N_PAD*256*2 -> 54361216
    unsigned short* h1rbf= (unsigned short*)(w + 54361216);   // -> 79985792
    unsigned short* h2bf = (unsigned short*)(w + 79985792);   // N_PAD*64*2 -> 86391936
    float* h2out    = (float*)(w + 86391936);     // 12.8 MB -> 99191936

    hipMemsetAsync(d_ws, 0, zbytes, stream);
    ea_sum_kernel<<<512, 256, 0, stream>>>(ea, scalars, N_EDGES);
    scalars_kernel<<<1, 64, 0, stream>>>(scalars, We1, ae1, We2, ae2);
    bcount_kernel<<<(ET + 255) / 256, 256, 0, stream>>>(ei, bcount);
    bscan_kernel<<<1, 1024, 0, stream>>>(bcount, bstart, bcur);
    binscatter_kernel<<<(ET + 255) / 256, 256, 0, stream>>>(ei, ea, scalars, bcur, bstage);
    bucketfill_kernel<<<NB, 256, 0, stream>>>(bstart, bstage, rowstart, csr);
    gstart_kernel<<<1, 192, 0, stream>>>(bidx, gstart);
    wcast_kernel<<<128, 256, 0, stream>>>(W1, W2, W1t, W2t);

    gemm_mfma<128, 16, true, 4><<<N_PAD / 64, 256, 0, stream>>>(
        x, W1t, h1bf, as1, ad1, asrc1, adst1, N_NODES);
    agg1_kernel<<<12500, 256, 0, stream>>>(rowstart, csr, asrc1, adst1,
                                           scalars, h1bf, b1, h1rbf);
    gemm_mfma<256, 4, false, 1><<<N_PAD / 64, 256, 0, stream>>>(
        h1rbf, W2t, h2bf, as2, ad2, asrc2, adst2, N_NODES);
    agg2_kernel<<<12500, 256, 0, stream>>>(rowstart, csr, asrc2, adst2,
                                           scalars, h2bf, b2, h2out);
    pool_mlp_kernel<<<G_GRAPHS, 256, 0, stream>>>(h2out, gstart, Wl1, bl1, lng, lnb,
                                                  Wl2, bl2, out);
    copy_ea_kernel<<<2048, 256, 0, stream>>>(ea, out + 2048);
}

// Round 13
// 518.534 us; speedup vs baseline: 1.3995x; 1.3995x over previous
//
#include <hip/hip_runtime.h>
#include <hip/hip_bf16.h>

#define N_NODES 50000
#define N_PAD 50048           // padded rows for MFMA tiles (multiple of 64)
#define N_EDGES 1600000
#define ET (N_EDGES + N_NODES)
#define G_GRAPHS 128
#define NB2 196               // 256-node buckets: 196*256 = 50176 >= 50000
#define CHUNK 8192
#define NCHUNK ((ET + CHUNK - 1) / CHUNK)   // 202
#define LOG2E 1.4426950408889634f

typedef unsigned short ushort8v __attribute__((ext_vector_type(8)));
typedef unsigned short ushort4v __attribute__((ext_vector_type(4)));
typedef short bf16x8 __attribute__((ext_vector_type(8)));
typedef float f32x4 __attribute__((ext_vector_type(4)));

__device__ __forceinline__ float bf2f(unsigned short u)
{
    return __uint_as_float(((unsigned int)u) << 16);
}
__device__ __forceinline__ unsigned short f2bf(float f)
{
    unsigned int u = __float_as_uint(f);
    u = (u + 0x7FFFu + ((u >> 16) & 1u)) >> 16;
    return (unsigned short)u;
}
__device__ __forceinline__ float exp2fast(float x) { return __builtin_amdgcn_exp2f(x); }
__device__ __forceinline__ float lrelu(float x) { return fmaxf(x, 0.2f * x); }

// ---------------- small utility kernels ----------------

__global__ void ea_sum_kernel(const float* __restrict__ ea, float* __restrict__ out, int n)
{
    float s = 0.f;
    for (int i = blockIdx.x * blockDim.x + threadIdx.x; i < n; i += gridDim.x * blockDim.x)
        s += ea[i];
    #pragma unroll
    for (int off = 32; off; off >>= 1) s += __shfl_xor(s, off);
    if ((threadIdx.x & 63) == 0) atomicAdd(out, s);
}

// ws scalars layout: [0]=ea_sum [1]=ea_mean [2..5]=c1[4]*log2e [6]=c2*log2e
__global__ void scalars_kernel(float* __restrict__ ws,
                               const float* __restrict__ We1, const float* __restrict__ ae1,
                               const float* __restrict__ We2, const float* __restrict__ ae2)
{
    if (threadIdx.x == 0 && blockIdx.x == 0) {
        ws[1] = ws[0] / (float)N_EDGES;
        for (int h = 0; h < 4; ++h) {
            float c = 0.f;
            for (int o = 0; o < 64; ++o) c += We1[h * 64 + o] * ae1[h * 64 + o];
            ws[2 + h] = c * LOG2E;
        }
        float c2 = 0.f;
        for (int o = 0; o < 64; ++o) c2 += We2[o] * ae2[o];
        ws[6] = c2 * LOG2E;
    }
}

// pass A: per-chunk LDS bucket count -> global bcount (196 atomics per block)
__global__ __launch_bounds__(256) void binA_kernel(const int* __restrict__ ei,
                                                   int* __restrict__ bcount)
{
    __shared__ int cnt[NB2];
    int tid = threadIdx.x;
    if (tid < NB2) cnt[tid] = 0;
    __syncthreads();
    int c0 = blockIdx.x * CHUNK, c1 = min(c0 + CHUNK, ET);
    for (int e = c0 + tid; e < c1; e += 256) {
        int dst = (e < N_EDGES) ? ei[N_EDGES + e] : (e - N_EDGES);
        atomicAdd(&cnt[dst >> 8], 1);
    }
    __syncthreads();
    if (tid < NB2 && cnt[tid]) atomicAdd(&bcount[tid], cnt[tid]);
}

// prefix over NB2 bucket counts -> bstart[NB2+1], bcur[NB2]
__global__ __launch_bounds__(256) void bscan_kernel(const int* __restrict__ bcount,
                                                    int* __restrict__ bstart,
                                                    int* __restrict__ bcur)
{
    __shared__ int s[256];
    int tid = threadIdx.x;
    int v = (tid < NB2) ? bcount[tid] : 0;
    s[tid] = v;
    __syncthreads();
    for (int off = 1; off < 256; off <<= 1) {
        int t = (tid >= off) ? s[tid - off] : 0;
        __syncthreads();
        s[tid] += t;
        __syncthreads();
    }
    int ex = s[tid] - v;
    if (tid < NB2) { bstart[tid] = ex; bcur[tid] = ex; }
    if (tid == 0) bstart[NB2] = ET;
}

// pass B: re-count chunk in LDS, reserve one contiguous run per bucket, write grouped
// records {ea:32 | src:16 | dstlo:8}. Runs are block-owned -> full-line writebacks.
__global__ __launch_bounds__(256) void binB_kernel(const int* __restrict__ ei,
                                                   const float* __restrict__ ea,
                                                   const float* __restrict__ ws,
                                                   int* __restrict__ bcur,
                                                   unsigned long long* __restrict__ bstage)
{
    __shared__ int cnt[NB2];
    __shared__ int base[NB2];
    int tid = threadIdx.x;
    if (tid < NB2) cnt[tid] = 0;
    __syncthreads();
    int c0 = blockIdx.x * CHUNK, c1 = min(c0 + CHUNK, ET);
    for (int e = c0 + tid; e < c1; e += 256) {
        int dst = (e < N_EDGES) ? ei[N_EDGES + e] : (e - N_EDGES);
        atomicAdd(&cnt[dst >> 8], 1);
    }
    __syncthreads();
    if (tid < NB2) {
        int c = cnt[tid];
        base[tid] = c ? atomicAdd(&bcur[tid], c) : 0;
        cnt[tid] = 0;   // reuse as local offset
    }
    __syncthreads();
    float mean = ws[1];
    for (int e = c0 + tid; e < c1; e += 256) {
        int src, dst; float v;
        if (e < N_EDGES) { src = ei[e]; dst = ei[N_EDGES + e]; v = ea[e]; }
        else             { src = dst = e - N_EDGES; v = mean; }
        int b = dst >> 8;
        int k = atomicAdd(&cnt[b], 1);
        unsigned long long rec = ((unsigned long long)__float_as_uint(v) << 32)
                               | ((unsigned)src << 8) | (unsigned)(dst & 255);
        bstage[base[b] + k] = rec;
    }
}

// per-bucket (256 nodes): LDS degree count -> rowstart -> L2-local reorder into CSR
__global__ __launch_bounds__(256) void bucketfill_kernel(const int* __restrict__ bstart,
                                                         const unsigned long long* __restrict__ bstage,
                                                         int* __restrict__ rowstart,
                                                         uint2* __restrict__ csr)
{
    __shared__ int lcnt[256];
    __shared__ int lcur[256];
    int b = blockIdx.x;
    int s = bstart[b], e = bstart[b + 1];
    int tid = threadIdx.x;
    lcnt[tid] = 0;
    __syncthreads();
    for (int p = s + tid; p < e; p += 256)
        atomicAdd(&lcnt[(int)(bstage[p] & 255)], 1);
    __syncthreads();
    if (tid == 0) {
        int run = s;
        for (int i = 0; i < 256; ++i) {
            int node = b * 256 + i;
            lcur[i] = run;
            if (node < N_NODES) rowstart[node] = run;
            run += lcnt[i];
        }
        if (b == NB2 - 1) rowstart[N_NODES] = ET;
    }
    __syncthreads();
    for (int p = s + tid; p < e; p += 256) {
        unsigned long long rec = bstage[p];
        int pos = atomicAdd(&lcur[(int)(rec & 255)], 1);
        csr[pos] = make_uint2((unsigned)((rec >> 8) & 0xFFFFu), (unsigned)(rec >> 32));
    }
}

// graph start offsets in the sorted batch_idx (129 entries)
__global__ void gstart_kernel(const int* __restrict__ bidx, int* __restrict__ gstart)
{
    int g = blockIdx.x * blockDim.x + threadIdx.x;
    if (g > G_GRAPHS) return;
    int lo = 0, hi = N_NODES;
    while (lo < hi) { int mid = (lo + hi) >> 1; if (bidx[mid] < g) lo = mid + 1; else hi = mid; }
    gstart[g] = lo;
}

// transpose+cast weights: W1[128][256]->W1t[256][128] bf16; W2[256][64]->W2t[64][256] bf16
__global__ void wcast_kernel(const float* __restrict__ W1, const float* __restrict__ W2,
                             unsigned short* __restrict__ W1t, unsigned short* __restrict__ W2t)
{
    int i = blockIdx.x * blockDim.x + threadIdx.x;
    if (i < 128 * 256) { int k = i >> 8, c = i & 255; W1t[c * 128 + k] = f2bf(W1[i]); }
    if (i < 256 * 64)  { int k = i >> 6, c = i & 63;  W2t[c * 256 + k] = f2bf(W2[i]); }
}

// ---------------- MFMA bf16 GEMM + fused alpha projections ----------------
template <int K, int NCB, bool A_F32, int NHEADS>
__global__ __launch_bounds__(256) void gemm_mfma(const void* __restrict__ Av,
                                                 const unsigned short* __restrict__ Wt,
                                                 unsigned short* __restrict__ C,
                                                 const float* __restrict__ a_s,
                                                 const float* __restrict__ a_d,
                                                 float* __restrict__ asrc,
                                                 float* __restrict__ adst,
                                                 int M)
{
    const int NC = NCB * 16;
    int wave = threadIdx.x >> 6, lane = threadIdx.x & 63;
    int l16 = lane & 15, lk = lane >> 4;
    int m = blockIdx.x * 64 + wave * 16 + l16;
    if (m >= M) m = M - 1;                 // clamp: tail lanes duplicate row M-1 (benign)
    f32x4 acc[NCB] = {};
    #pragma unroll
    for (int k0 = 0; k0 < K; k0 += 32) {
        int kk = k0 + lk * 8;
        bf16x8 af;
        if constexpr (A_F32) {
            const float* A = (const float*)Av;
            float4 u0 = *(const float4*)&A[(size_t)m * K + kk];
            float4 u1 = *(const float4*)&A[(size_t)m * K + kk + 4];
            af[0] = (short)f2bf(u0.x); af[1] = (short)f2bf(u0.y);
            af[2] = (short)f2bf(u0.z); af[3] = (short)f2bf(u0.w);
            af[4] = (short)f2bf(u1.x); af[5] = (short)f2bf(u1.y);
            af[6] = (short)f2bf(u1.z); af[7] = (short)f2bf(u1.w);
        } else {
            af = *(const bf16x8*)&((const unsigned short*)Av)[(size_t)m * K + kk];
        }
        #pragma unroll
        for (int cb = 0; cb < NCB; ++cb) {
            bf16x8 wf = *(const bf16x8*)&Wt[(size_t)(cb * 16 + l16) * K + kk];
            acc[cb] = __builtin_amdgcn_mfma_f32_16x16x32_bf16(wf, af, acc[cb], 0, 0, 0);
        }
    }
    float sa[NHEADS], da[NHEADS];
    #pragma unroll
    for (int h = 0; h < NHEADS; ++h) { sa[h] = 0.f; da[h] = 0.f; }
    #pragma unroll
    for (int cb = 0; cb < NCB; ++cb) {
        const int hh = (NHEADS == 4) ? (cb >> 2) : 0;
        ushort4v o;
        #pragma unroll
        for (int j = 0; j < 4; ++j) {
            o[j] = f2bf(acc[cb][j]);
            float v = bf2f(o[j]);           // use rounded value (matches gather path)
            int c = cb * 16 + lk * 4 + j;
            sa[hh] = fmaf(v, a_s[c], sa[hh]);
            da[hh] = fmaf(v, a_d[c], da[hh]);
        }
        *(ushort4v*)&C[(size_t)m * NC + cb * 16 + lk * 4] = o;
    }
    #pragma unroll
    for (int h = 0; h < NHEADS; ++h) {
        sa[h] += __shfl_xor(sa[h], 16); sa[h] += __shfl_xor(sa[h], 32);
        da[h] += __shfl_xor(da[h], 16); da[h] += __shfl_xor(da[h], 32);
    }
    if (lk == 0) {
        if constexpr (NHEADS == 4) {
            float4 vs = make_float4(sa[0] * LOG2E, sa[1] * LOG2E, sa[2] * LOG2E, sa[3] * LOG2E);
            float4 vd = make_float4(da[0] * LOG2E, da[1] * LOG2E, da[2] * LOG2E, da[3] * LOG2E);
            *(float4*)&asrc[(size_t)m * 4] = vs;
            *(float4*)&adst[(size_t)m * 4] = vd;
        } else {
            asrc[m] = sa[0] * LOG2E;
            adst[m] = da[0] * LOG2E;
        }
    }
}

// ---------------- layer 1: single-pass softmax-aggregate (exp2 domain) ----------------
// 2 lane-groups x 32 lanes; lane covers 8 channels; 8 loads = 16 edges/iter.

__global__ __launch_bounds__(256) void agg1_kernel(const int* __restrict__ rowstart,
                                                   const uint2* __restrict__ csr,
                                                   const float* __restrict__ asrc,
                                                   const float* __restrict__ adst,
                                                   const float* __restrict__ ws,
                                                   const unsigned short* __restrict__ h1bf,
                                                   const float* __restrict__ b1,
                                                   unsigned short* __restrict__ h1rbf)
{
    int wid  = (blockIdx.x * blockDim.x + threadIdx.x) >> 6;
    int lane = threadIdx.x & 63;
    if (wid >= N_NODES) return;
    int rs = rowstart[wid], re = rowstart[wid + 1];
    int g   = lane >> 5;        // edge sub-slot (0..1)
    int sub = lane & 31;        // channel block: channels sub*8 .. sub*8+7
    int hh  = sub >> 3;         // head of this lane's channels
    float ad_s = adst[(size_t)wid * 4 + hh];
    float c_s  = ws[2 + hh];

    float acc[8] = {};
    float sden = 0.f;
    for (int p = rs; p < re; p += 16) {
        #pragma unroll
        for (int k = 0; k < 8; ++k) {
            int pe = p + 2 * k + g;
            bool act = pe < re;
            int idx = act ? pe : re - 1;
            uint2 q = csr[idx];
            int src  = (int)q.x;
            float ev = __uint_as_float(q.y);
            ushort8v r = *(const ushort8v*)&h1bf[(size_t)src * 256 + sub * 8];
            float al = lrelu(fmaf(ev, c_s, asrc[(size_t)src * 4 + hh] + ad_s));
            float wgt = act ? exp2fast(al) : 0.f;
            sden += wgt;
            #pragma unroll
            for (int j = 0; j < 8; ++j)
                acc[j] = fmaf(bf2f(r[j]), wgt, acc[j]);
        }
    }
    sden += __shfl_xor(sden, 32);
    #pragma unroll
    for (int j = 0; j < 8; ++j) acc[j] += __shfl_xor(acc[j], 32);
    float inv = 1.0f / (sden + 1e-16f);
    if (g == 0) {
        float4 ba = *(const float4*)&b1[sub * 8];
        float4 bb = *(const float4*)&b1[sub * 8 + 4];
        ushort8v ov;
        ov[0] = f2bf(fmaxf(fmaf(acc[0], inv, ba.x), 0.f));
        ov[1] = f2bf(fmaxf(fmaf(acc[1], inv, ba.y), 0.f));
        ov[2] = f2bf(fmaxf(fmaf(acc[2], inv, ba.z), 0.f));
        ov[3] = f2bf(fmaxf(fmaf(acc[3], inv, ba.w), 0.f));
        ov[4] = f2bf(fmaxf(fmaf(acc[4], inv, bb.x), 0.f));
        ov[5] = f2bf(fmaxf(fmaf(acc[5], inv, bb.y), 0.f));
        ov[6] = f2bf(fmaxf(fmaf(acc[6], inv, bb.z), 0.f));
        ov[7] = f2bf(fmaxf(fmaf(acc[7], inv, bb.w), 0.f));
        *(ushort8v*)&h1rbf[(size_t)wid * 256 + sub * 8] = ov;
    }
}

// ---------------- layer 2 (H=1): single-pass softmax-aggregate, direct store ----------------
// 8 lane-groups x 8 lanes; lane covers 8 channels; 4 loads = 32 edges/iter.

__global__ __launch_bounds__(256) void agg2_kernel(const int* __restrict__ rowstart,
                                                   const uint2* __restrict__ csr,
                                                   const float* __restrict__ asrc,
                                                   const float* __restrict__ adst,
                                                   const float* __restrict__ ws,
                                                   const unsigned short* __restrict__ h2bf,
                                                   const float* __restrict__ b2,
                                                   float* __restrict__ h2out)
{
    int wid  = (blockIdx.x * blockDim.x + threadIdx.x) >> 6;
    int lane = threadIdx.x & 63;
    if (wid >= N_NODES) return;
    int rs = rowstart[wid], re = rowstart[wid + 1];
    float c2 = ws[6];
    float ad = adst[wid];
    int g   = lane >> 3;   // edge sub-slot (0..7)
    int sub = lane & 7;    // channel block: channels sub*8 .. sub*8+7
    float acc[8] = {};
    float sden = 0.f;
    for (int p = rs; p < re; p += 32) {
        #pragma unroll
        for (int k = 0; k < 4; ++k) {
            int pe = p + 8 * k + g;
            bool act = pe < re;
            int idx = act ? pe : re - 1;
            uint2 q = csr[idx];
            int src  = (int)q.x;
            float ev = __uint_as_float(q.y);
            ushort8v r = *(const ushort8v*)&h2bf[(size_t)src * 64 + sub * 8];
            float al = lrelu(fmaf(ev, c2, asrc[src] + ad));
            float wgt = act ? exp2fast(al) : 0.f;
            sden += wgt;
            #pragma unroll
            for (int j = 0; j < 8; ++j)
                acc[j] = fmaf(bf2f(r[j]), wgt, acc[j]);
        }
    }
    sden += __shfl_xor(sden, 8);
    sden += __shfl_xor(sden, 16);
    sden += __shfl_xor(sden, 32);
    #pragma unroll
    for (int j = 0; j < 8; ++j) {
        acc[j] += __shfl_xor(acc[j], 8);
        acc[j] += __shfl_xor(acc[j], 16);
        acc[j] += __shfl_xor(acc[j], 32);
    }
    float inv = 1.0f / (sden + 1e-16f);
    if (g == 0) {
        float4 ba = *(const float4*)&b2[sub * 8];
        float4 bb = *(const float4*)&b2[sub * 8 + 4];
        float4 o0, o1;
        o0.x = fmaf(acc[0], inv, ba.x); o0.y = fmaf(acc[1], inv, ba.y);
        o0.z = fmaf(acc[2], inv, ba.z); o0.w = fmaf(acc[3], inv, ba.w);
        o1.x = fmaf(acc[4], inv, bb.x); o1.y = fmaf(acc[5], inv, bb.y);
        o1.z = fmaf(acc[6], inv, bb.z); o1.w = fmaf(acc[7], inv, bb.w);
        float* o = h2out + (size_t)wid * 64 + sub * 8;
        *(float4*)&o[0] = o0;
        *(float4*)&o[4] = o1;
    }
}

// ---------------- fused mean pool + MLP head: one block per graph ----------------

__global__ __launch_bounds__(256) void pool_mlp_kernel(const float* __restrict__ h2out,
                                                       const int* __restrict__ gstart,
                                                       const float* __restrict__ Wl1,
                                                       const float* __restrict__ bl1,
                                                       const float* __restrict__ lng,
                                                       const float* __restrict__ lnb,
                                                       const float* __restrict__ Wl2,
                                                       const float* __restrict__ bl2,
                                                       float* __restrict__ out)
{
    __shared__ float sh[4][64];
    __shared__ float gs[64], zs[64];
    int g = blockIdx.x;
    int wv = threadIdx.x >> 6, lane = threadIdx.x & 63;
    int s = gstart[g], e = gstart[g + 1];
    float acc = 0.f;
    for (int n = s + wv; n < e; n += 4)
        acc += h2out[(size_t)n * 64 + lane];
    sh[wv][lane] = acc;
    __syncthreads();
    int l = threadIdx.x;
    if (l < 64) {
        float cnt = fmaxf((float)(e - s), 1.f);
        gs[l] = (sh[0][l] + sh[1][l] + sh[2][l] + sh[3][l]) / cnt;
    }
    __syncthreads();
    if (l < 64) {
        float z = bl1[l];
        for (int k = 0; k < 64; ++k) z = fmaf(gs[k], Wl1[k * 64 + l], z);
        z = fmaxf(z, 0.f);
        float sum = z;
        #pragma unroll
        for (int off = 32; off; off >>= 1) sum += __shfl_xor(sum, off);
        float mu = sum * (1.f / 64.f);
        float d  = z - mu;
        float vs = d * d;
        #pragma unroll
        for (int off = 32; off; off >>= 1) vs += __shfl_xor(vs, off);
        float var = vs * (1.f / 64.f);
        zs[l] = d * rsqrtf(var + 1e-5f) * lng[l] + lnb[l];
    }
    __syncthreads();
    if (l < 16) {
        float o = bl2[l];
        for (int k = 0; k < 64; ++k) o = fmaf(zs[k], Wl2[k * 16 + l], o);
        out[g * 16 + l] = o;
    }
}

__global__ void copy_ea_kernel(const float* __restrict__ ea, float* __restrict__ out)
{
    for (int i = blockIdx.x * blockDim.x + threadIdx.x; i < N_EDGES; i += gridDim.x * blockDim.x)
        out[i] = ea[i];
}

// ---------------- launch ----------------

extern "C" void kernel_launch(void* const* d_in, const int* in_sizes, int n_in,
                              void* d_out, int out_size, void* d_ws, size_t ws_size,
                              hipStream_t stream)
{
    const float* x    = (const float*)d_in[0];
    const int*   ei   = (const int*)d_in[1];
    const float* ea   = (const float*)d_in[2];
    const int*   bidx = (const int*)d_in[3];
    const float* W1   = (const float*)d_in[4];
    const float* as1  = (const float*)d_in[5];
    const float* ad1  = (const float*)d_in[6];
    const float* We1  = (const float*)d_in[7];
    const float* ae1  = (const float*)d_in[8];
    const float* b1   = (const float*)d_in[9];
    const float* W2   = (const float*)d_in[10];
    const float* as2  = (const float*)d_in[11];
    const float* ad2  = (const float*)d_in[12];
    const float* We2  = (const float*)d_in[13];
    const float* ae2  = (const float*)d_in[14];
    const float* b2   = (const float*)d_in[15];
    const float* Wl1  = (const float*)d_in[16];
    const float* bl1  = (const float*)d_in[17];
    const float* lng  = (const float*)d_in[18];
    const float* lnb  = (const float*)d_in[19];
    const float* Wl2  = (const float*)d_in[20];
    const float* bl2  = (const float*)d_in[21];
    float* out = (float*)d_out;

    char* w = (char*)d_ws;
    float* scalars  = (float*)(w + 0);            // 64 B
    int*   bcount   = (int*)  (w + 64);           // 784 B -> zero first 1024
    const size_t zbytes = 1024;
    int*   bstart   = (int*)  (w + 1024);         // 788 B
    int*   bcur     = (int*)  (w + 2048);         // 784 B
    int*   rowstart = (int*)  (w + 4096);         // 200004 B -> 204100
    int*   gstart   = (int*)  (w + 204160);       // 516 B -> 204676
    unsigned long long* bstage = (unsigned long long*)(w + 204736);  // 13.2 MB -> 13404736
    uint2* csr      = (uint2*)(w + 13404736);     // 13.2 MB -> 26604736
    float* asrc1    = (float*)(w + 26604736);     // 800 KB
    float* adst1    = (float*)(w + 27404736);     // 800 KB
    float* asrc2    = (float*)(w + 28204736);     // 200 KB
    float* adst2    = (float*)(w + 28404736);     // 200 KB -> 28604736
    unsigned short* W1t  = (unsigned short*)(w + 28604736);   // 64 KB -> 28670272
    unsigned short* W2t  = (unsigned short*)(w + 28670272);   // 32 KB -> 28703040
    unsigned short* h1bf = (unsigned short*)(w + 28703040);   // N_PAD*256*2 -> 54327616
    unsigned short* h1rbf= (unsigned short*)(w + 54327616);   // -> 79952192
    unsigned short* h2bf = (unsigned short*)(w + 79952192);   // N_PAD*64*2 -> 86358336
    float* h2out    = (float*)(w + 86358336);     // 12.8 MB -> 99158336

    hipMemsetAsync(d_ws, 0, zbytes, stream);
    ea_sum_kernel<<<512, 256, 0, stream>>>(ea, scalars, N_EDGES);
    scalars_kernel<<<1, 64, 0, stream>>>(scalars, We1, ae1, We2, ae2);
    binA_kernel<<<NCHUNK, 256, 0, stream>>>(ei, bcount);
    bscan_kernel<<<1, 256, 0, stream>>>(bcount, bstart, bcur);
    binB_kernel<<<NCHUNK, 256, 0, stream>>>(ei, ea, scalars, bcur, bstage);
    bucketfill_kernel<<<NB2, 256, 0, stream>>>(bstart, bstage, rowstart, csr);
    gstart_kernel<<<1, 192, 0, stream>>>(bidx, gstart);
    wcast_kernel<<<128, 256, 0, stream>>>(W1, W2, W1t, W2t);

    gemm_mfma<128, 16, true, 4><<<N_PAD / 64, 256, 0, stream>>>(
        x, W1t, h1bf, as1, ad1, asrc1, adst1, N_NODES);
    agg1_kernel<<<12500, 256, 0, stream>>>(rowstart, csr, asrc1, adst1,
                                           scalars, h1bf, b1, h1rbf);
    gemm_mfma<256, 4, false, 1><<<N_PAD / 64, 256, 0, stream>>>(
        h1rbf, W2t, h2bf, as2, ad2, asrc2, adst2, N_NODES);
    agg2_kernel<<<12500, 256, 0, stream>>>(rowstart, csr, asrc2, adst2,
                                           scalars, h2bf, b2, h2out);
    pool_mlp_kernel<<<G_GRAPHS, 256, 0, stream>>>(h2out, gstart, Wl1, bl1, lng, lnb,
                                                  Wl2, bl2, out);
    copy_ea_kernel<<<2048, 256, 0, stream>>>(ea, out + 2048);
}